// Round 1
// baseline (430.802 us; speedup 1.0000x reference)
//
#include <hip/hip_runtime.h>

#define N_NODES 100000
#define N_EDGES 1600000
#define EMBED_DIM 64

// One wave (64 lanes) per edge: lane d handles embedding dim d.
// vals/rows/cols are wave-uniform -> scalar loads; X gather is one
// coalesced 256B read per wave; scatter via fp32 atomicAdd.
__global__ __launch_bounds__(256) void spmm_scatter_kernel(
    const float* __restrict__ x,       // [N_NODES, 64]
    const float* __restrict__ vals,    // [E]
    const int*   __restrict__ rows,    // [E]
    const int*   __restrict__ cols,    // [E]
    float* __restrict__ out)           // [N_NODES, 64]
{
    const int wave_in_block = threadIdx.x >> 6;   // 0..3
    const int lane          = threadIdx.x & 63;   // dim index
    const int e = blockIdx.x * 4 + wave_in_block;
    if (e >= N_EDGES) return;

    const float v = vals[e];
    const int   c = cols[e];
    const int   r = rows[e];

    const float m = v * x[(size_t)c * EMBED_DIM + lane];
    atomicAdd(&out[(size_t)r * EMBED_DIM + lane], m);
}

extern "C" void kernel_launch(void* const* d_in, const int* in_sizes, int n_in,
                              void* d_out, int out_size, void* d_ws, size_t ws_size,
                              hipStream_t stream) {
    const float* x    = (const float*)d_in[0];  // ego_embeddings [N,64]
    const float* vals = (const float*)d_in[1];  // adj_values [E]
    const int*   rows = (const int*)d_in[2];    // adj_rows [E]
    const int*   cols = (const int*)d_in[3];    // adj_cols [E]
    float* out = (float*)d_out;                 // [N,64] fp32

    // d_out is re-poisoned (0xAA) before every timed launch -> zero it.
    hipMemsetAsync(out, 0, (size_t)out_size * sizeof(float), stream);

    const int blocks = (N_EDGES + 3) / 4;  // 4 edges (waves) per 256-thread block
    spmm_scatter_kernel<<<blocks, 256, 0, stream>>>(x, vals, rows, cols, out);
}

// Round 2
// 336.721 us; speedup vs baseline: 1.2794x; 1.2794x over previous
//
#include <hip/hip_runtime.h>

#define N_NODES 100000
#define N_EDGES 1600000
#define EMBED_DIM 64

#define SCAN_BLK 256
#define SCAN_ITEMS 4
#define SCAN_CHUNK (SCAN_BLK * SCAN_ITEMS)            // 1024
#define SCAN_NB ((N_NODES + SCAN_CHUNK - 1) / SCAN_CHUNK)  // 98

// ---------- pass 1: histogram of rows ----------
__global__ __launch_bounds__(256) void k_hist(const int* __restrict__ rows,
                                              int* __restrict__ cnt) {
    int e = blockIdx.x * 256 + threadIdx.x;
    if (e < N_EDGES) atomicAdd(&cnt[rows[e]], 1);
}

// ---------- pass 2a: per-block reduce of cnt ----------
__global__ __launch_bounds__(SCAN_BLK) void k_reduce(const int* __restrict__ cnt,
                                                     int* __restrict__ bsum) {
    __shared__ int s[SCAN_BLK];
    int tid = threadIdx.x;
    int base = blockIdx.x * SCAN_CHUNK + tid * SCAN_ITEMS;
    int t = 0;
#pragma unroll
    for (int i = 0; i < SCAN_ITEMS; ++i) {
        int idx = base + i;
        if (idx < N_NODES) t += cnt[idx];
    }
    s[tid] = t;
    __syncthreads();
    for (int off = SCAN_BLK / 2; off > 0; off >>= 1) {
        if (tid < off) s[tid] += s[tid + off];
        __syncthreads();
    }
    if (tid == 0) bsum[blockIdx.x] = s[0];
}

// ---------- pass 2b: exclusive scan of block sums (single block) ----------
__global__ __launch_bounds__(128) void k_scan_bsum(int* __restrict__ bsum,
                                                   int* __restrict__ row_ptr) {
    __shared__ int s[128];
    int tid = threadIdx.x;
    s[tid] = (tid < SCAN_NB) ? bsum[tid] : 0;
    __syncthreads();
    for (int off = 1; off < 128; off <<= 1) {
        int v = s[tid];
        int add = (tid >= off) ? s[tid - off] : 0;
        __syncthreads();
        s[tid] = v + add;
        __syncthreads();
    }
    if (tid < SCAN_NB) bsum[tid] = (tid == 0) ? 0 : s[tid - 1];
    if (tid == 0) row_ptr[N_NODES] = N_EDGES;
}

// ---------- pass 2c: final scan -> row_ptr + cursor ----------
__global__ __launch_bounds__(SCAN_BLK) void k_scan_final(const int* __restrict__ cnt,
                                                         const int* __restrict__ bsum,
                                                         int* __restrict__ row_ptr,
                                                         int* __restrict__ cursor) {
    __shared__ int s[SCAN_BLK];
    int tid = threadIdx.x;
    int base = blockIdx.x * SCAN_CHUNK + tid * SCAN_ITEMS;
    int v[SCAN_ITEMS];
    int t = 0;
#pragma unroll
    for (int i = 0; i < SCAN_ITEMS; ++i) {
        int idx = base + i;
        v[i] = (idx < N_NODES) ? cnt[idx] : 0;
        t += v[i];
    }
    s[tid] = t;
    __syncthreads();
    for (int off = 1; off < SCAN_BLK; off <<= 1) {
        int a = s[tid];
        int add = (tid >= off) ? s[tid - off] : 0;
        __syncthreads();
        s[tid] = a + add;
        __syncthreads();
    }
    int run = ((tid == 0) ? 0 : s[tid - 1]) + bsum[blockIdx.x];
#pragma unroll
    for (int i = 0; i < SCAN_ITEMS; ++i) {
        int idx = base + i;
        if (idx < N_NODES) {
            row_ptr[idx] = run;
            cursor[idx] = run;
        }
        run += v[i];
    }
}

// ---------- pass 3: bucket-scatter (col,val) into CSR order ----------
__global__ __launch_bounds__(256) void k_scatter(const int* __restrict__ rows,
                                                 const int* __restrict__ cols,
                                                 const float* __restrict__ vals,
                                                 int* __restrict__ cursor,
                                                 int* __restrict__ sc,
                                                 float* __restrict__ sv) {
    int e = blockIdx.x * 256 + threadIdx.x;
    if (e >= N_EDGES) return;
    int r = rows[e];
    int p = atomicAdd(&cursor[r], 1);
    sc[p] = cols[e];
    sv[p] = vals[e];
}

// ---------- pass 4: one wave per row, register-accumulate, single write ----------
__global__ __launch_bounds__(256) void k_gather(const float* __restrict__ x,
                                                const int* __restrict__ row_ptr,
                                                const int* __restrict__ sc,
                                                const float* __restrict__ sv,
                                                float* __restrict__ out) {
    int wid = (blockIdx.x * 256 + threadIdx.x) >> 6;  // row id
    int lane = threadIdx.x & 63;                      // dim id
    if (wid >= N_NODES) return;
    int beg = row_ptr[wid];
    int end = row_ptr[wid + 1];
    float acc = 0.f;
    int e = beg;
    for (; e + 4 <= end; e += 4) {
        int c0 = sc[e], c1 = sc[e + 1], c2 = sc[e + 2], c3 = sc[e + 3];
        float v0 = sv[e], v1 = sv[e + 1], v2 = sv[e + 2], v3 = sv[e + 3];
        float x0 = x[c0 * EMBED_DIM + lane];
        float x1 = x[c1 * EMBED_DIM + lane];
        float x2 = x[c2 * EMBED_DIM + lane];
        float x3 = x[c3 * EMBED_DIM + lane];
        acc += v0 * x0;
        acc += v1 * x1;
        acc += v2 * x2;
        acc += v3 * x3;
    }
    for (; e < end; ++e) acc += sv[e] * x[sc[e] * EMBED_DIM + lane];
    out[wid * EMBED_DIM + lane] = acc;
}

// ---------- fallback (ws too small): round-1 atomic scatter ----------
__global__ __launch_bounds__(256) void spmm_scatter_kernel(
    const float* __restrict__ x, const float* __restrict__ vals,
    const int* __restrict__ rows, const int* __restrict__ cols,
    float* __restrict__ out) {
    const int wave_in_block = threadIdx.x >> 6;
    const int lane = threadIdx.x & 63;
    const int e = blockIdx.x * 4 + wave_in_block;
    if (e >= N_EDGES) return;
    const float m = vals[e] * x[cols[e] * EMBED_DIM + lane];
    atomicAdd(&out[rows[e] * EMBED_DIM + lane], m);
}

extern "C" void kernel_launch(void* const* d_in, const int* in_sizes, int n_in,
                              void* d_out, int out_size, void* d_ws, size_t ws_size,
                              hipStream_t stream) {
    const float* x    = (const float*)d_in[0];
    const float* vals = (const float*)d_in[1];
    const int*   rows = (const int*)d_in[2];
    const int*   cols = (const int*)d_in[3];
    float* out = (float*)d_out;

    // Workspace layout (ints):
    //   row_ptr : N+1
    //   cnt     : N
    //   cursor  : N
    //   bsum    : 128
    //   sc      : E (int)   sv : E (float)
    const size_t need = ((size_t)(3 * N_NODES + 1 + 128) + 2 * (size_t)N_EDGES) * 4;
    if (ws_size < need) {
        hipMemsetAsync(out, 0, (size_t)out_size * sizeof(float), stream);
        spmm_scatter_kernel<<<(N_EDGES + 3) / 4, 256, 0, stream>>>(x, vals, rows, cols, out);
        return;
    }

    int* row_ptr = (int*)d_ws;
    int* cnt     = row_ptr + (N_NODES + 1);
    int* cursor  = cnt + N_NODES;
    int* bsum    = cursor + N_NODES;
    int* sc      = bsum + 128;
    float* sv    = (float*)(sc + N_EDGES);

    hipMemsetAsync(cnt, 0, (size_t)N_NODES * sizeof(int), stream);

    k_hist<<<(N_EDGES + 255) / 256, 256, 0, stream>>>(rows, cnt);
    k_reduce<<<SCAN_NB, SCAN_BLK, 0, stream>>>(cnt, bsum);
    k_scan_bsum<<<1, 128, 0, stream>>>(bsum, row_ptr);
    k_scan_final<<<SCAN_NB, SCAN_BLK, 0, stream>>>(cnt, bsum, row_ptr, cursor);
    k_scatter<<<(N_EDGES + 255) / 256, 256, 0, stream>>>(rows, cols, vals, cursor, sc, sv);
    k_gather<<<(N_NODES * 64 + 255) / 256, 256, 0, stream>>>(x, row_ptr, sc, sv, out);
}